// Round 7
// baseline (921.604 us; speedup 1.0000x reference)
//
#include <hip/hip_runtime.h>
#include <hip/hip_bf16.h>

// MoE: N=8192 tokens, D=1024, H=4096, E=8 experts, top-k=2.
// Grouped GEMMs: 256x256 tile, 8 waves, BK=32, 3-deep circular LDS buffer,
// counted vmcnt(4) + raw s_barrier (1 barrier/K-step), XOR bank swizzle.
// gemm2: atomic-free epilogue -> per-assignment f32 partials + combine kernel.

#define NTOK 8192
#define DDIM 1024
#define HDIM 4096
#define NEXP 8
#define NASSIGN (NTOK * 2)
#define MAX_MT 72               // max ceil-sum of per-expert 256-row tiles (71)
#define GRID1 (16 * MAX_MT)     // 1152, divisible by 8
#define GRID2A (4 * 2 * MAX_MT) // 576  (K-split x2, no atomics)
#define GRID2B (4 * MAX_MT)     // 288  (atomic fallback)

typedef __bf16 bf16_t;
typedef __bf16 bf16x2 __attribute__((ext_vector_type(2)));
typedef __bf16 bf16x4 __attribute__((ext_vector_type(4)));
typedef __bf16 bf16x8 __attribute__((ext_vector_type(8)));
typedef float f32x4 __attribute__((ext_vector_type(4)));

#define GLOAD16(gptr, lptr)                                                    \
  __builtin_amdgcn_global_load_lds(                                            \
      (const __attribute__((address_space(1))) void*)(gptr),                   \
      (__attribute__((address_space(3))) void*)(lptr), 16, 0, 0)

#define VMCNT(n) asm volatile("s_waitcnt vmcnt(" #n ")" ::: "memory")

// bijective XCD swizzle: launched id -> logical job; nwg % 8 == 0
__device__ __forceinline__ int xcd_swz(int orig, int nwg) {
  const int cpx = nwg >> 3;
  return (orig & 7) * cpx + (orig >> 3);
}

// ---------------- weight transpose: [E][R][C] f32 -> [E][C][R] bf16 --------
__global__ void __launch_bounds__(256) transpose_cvt_kernel(
    const float* __restrict__ in, bf16_t* __restrict__ out, int R, int C) {
  __shared__ float tile[64][33];
  const size_t mat = (size_t)R * C;
  const float* ip = in + (size_t)blockIdx.z * mat;
  bf16_t* op = out + (size_t)blockIdx.z * mat;
  const int c0 = blockIdx.x * 32, r0 = blockIdx.y * 64;
  const int tx = threadIdx.x, ty = threadIdx.y;  // (32, 8)
#pragma unroll
  for (int i = 0; i < 8; ++i) {
    const int r = ty + 8 * i;
    tile[r][tx] = ip[(size_t)(r0 + r) * C + (c0 + tx)];
  }
  __syncthreads();
#pragma unroll
  for (int j = 0; j < 4; ++j) {
    const int c = ty + 8 * j;
    bf16x2 v;
    v[0] = (bf16_t)tile[2 * tx][c];
    v[1] = (bf16_t)tile[2 * tx + 1][c];
    *(bf16x2*)(op + (size_t)(c0 + c) * R + r0 + 2 * tx) = v;
  }
}

// ---------------- router (fused x -> bf16; wave-shuffle reduce) ------------
__global__ void __launch_bounds__(256) router_kernel(
    const float* __restrict__ x, const float* __restrict__ Wr,
    const float* __restrict__ br, int2* __restrict__ ids,
    float2* __restrict__ prs, int* __restrict__ counts,
    bf16_t* __restrict__ xb) {
  const int n = blockIdx.x;
  const int t = threadIdx.x;
  const int wave = t >> 6, lane = t & 63;
  const float4 xv = ((const float4*)(x + (size_t)n * DDIM))[t];
  bf16x4 o;
  o[0] = (bf16_t)xv.x; o[1] = (bf16_t)xv.y;
  o[2] = (bf16_t)xv.z; o[3] = (bf16_t)xv.w;
  ((bf16x4*)(xb + (size_t)n * DDIM))[t] = o;

  float acc[NEXP];
#pragma unroll
  for (int e = 0; e < NEXP; ++e) acc[e] = 0.f;
  const float xq[4] = {xv.x, xv.y, xv.z, xv.w};
#pragma unroll
  for (int q = 0; q < 4; ++q) {
    const float* w = Wr + (size_t)(4 * t + q) * NEXP;
#pragma unroll
    for (int e = 0; e < NEXP; ++e) acc[e] += xq[q] * w[e];
  }
#pragma unroll
  for (int off = 32; off >= 1; off >>= 1)
#pragma unroll
    for (int e = 0; e < NEXP; ++e) acc[e] += __shfl_down(acc[e], off);
  __shared__ float red[4][NEXP];
  if (lane == 0)
#pragma unroll
    for (int e = 0; e < NEXP; ++e) red[wave][e] = acc[e];
  __syncthreads();
  if (t == 0) {
    float l[NEXP];
#pragma unroll
    for (int e = 0; e < NEXP; ++e)
      l[e] = ((red[0][e] + red[1][e]) + (red[2][e] + red[3][e])) + br[e];
    int i1 = 0; float v1 = l[0];
    for (int e = 1; e < NEXP; ++e)
      if (l[e] > v1) { v1 = l[e]; i1 = e; }
    int i2 = (i1 == 0) ? 1 : 0; float v2 = l[i2];
    for (int e = 0; e < NEXP; ++e)
      if (e != i1 && l[e] > v2) { v2 = l[e]; i2 = e; }
    float denom = 0.f;
    for (int e = 0; e < NEXP; ++e) denom += expf(l[e] - v1);
    ids[n] = make_int2(i1, i2);
    prs[n] = make_float2(1.f / denom, expf(v2 - v1) / denom);
    atomicAdd(&counts[i1], 1);
    atomicAdd(&counts[i2], 1);
  }
}

// scan (thread 0, 256-row tiles) + aux loss
__global__ void __launch_bounds__(256) scan_aux_kernel(
    const int* __restrict__ counts, int* __restrict__ offsets,
    int* __restrict__ tmap, const int2* __restrict__ ids,
    const float2* __restrict__ prs, float* __restrict__ aux_out) {
  const int t = threadIdx.x;
  if (t == 0) {
    int off = 0, nt = 0;
    for (int e = 0; e < NEXP; ++e) {
      offsets[e] = off;
      const int c = counts[e];
      for (int m0 = 0; m0 < c; m0 += 256) {
        tmap[nt] = e;
        tmap[MAX_MT + nt] = m0;
        ++nt;
      }
      off += c;
    }
    offsets[NEXP] = off;
    tmap[2 * MAX_MT] = nt;
  }
  float imp[NEXP];
#pragma unroll
  for (int e = 0; e < NEXP; ++e) imp[e] = 0.f;
  for (int n = t; n < NTOK; n += 256) {
    const int2 id = ids[n];
    const float2 pr = prs[n];
#pragma unroll
    for (int e = 0; e < NEXP; ++e)
      imp[e] += (id.x == e ? pr.x : 0.f) + (id.y == e ? pr.y : 0.f);
  }
  __shared__ float red[256][NEXP];
#pragma unroll
  for (int e = 0; e < NEXP; ++e) red[t][e] = imp[e];
  __syncthreads();
  for (int s = 128; s >= 1; s >>= 1) {
    if (t < s) {
#pragma unroll
      for (int e = 0; e < NEXP; ++e) red[t][e] += red[t + s][e];
    }
    __syncthreads();
  }
  if (t == 0) {
    float m = 0.f;
    for (int e = 0; e < NEXP; ++e) m += red[0][e];
    m *= (1.f / NEXP);
    float v = 0.f;
    for (int e = 0; e < NEXP; ++e) {
      const float d = red[0][e] - m;
      v += d * d;
    }
    v *= (1.f / (NEXP - 1));  // ddof=1
    aux_out[0] = v / (m * m + 1e-9f);
  }
}

// scatter: bucket tokens; also record token -> (assign1, assign2)
__global__ void __launch_bounds__(256) scatter_kernel(
    const int2* __restrict__ ids, const float2* __restrict__ prs,
    const int* __restrict__ offsets, int* __restrict__ cursor,
    int* __restrict__ btok, float* __restrict__ bprob,
    int2* __restrict__ amap) {
  const int n = blockIdx.x * 256 + threadIdx.x;
  if (n >= NTOK) return;
  const int2 id = ids[n];
  const float2 pr = prs[n];
  int p = atomicAdd(&cursor[id.x], 1);
  const int a1 = offsets[id.x] + p;
  btok[a1] = n;
  bprob[a1] = pr.x;
  p = atomicAdd(&cursor[id.y], 1);
  const int a2 = offsets[id.y] + p;
  btok[a2] = n;
  bprob[a2] = pr.y;
  amap[n] = make_int2(a1, a2);
}

// combine: out[n] = p1*(o0+o1)[a1] + p2*(o0+o1)[a2]  (bias already in o0)
__global__ void __launch_bounds__(256) combine_kernel(
    const float* __restrict__ o0, const float* __restrict__ o1,
    const int2* __restrict__ amap, const float* __restrict__ bprob,
    float* __restrict__ out) {
  const int n = blockIdx.x;
  const int d = threadIdx.x * 4;
  const int2 a = amap[n];
  const float p1 = bprob[a.x], p2 = bprob[a.y];
  const float4 u0 = *(const float4*)(o0 + (size_t)a.x * DDIM + d);
  const float4 u1 = *(const float4*)(o1 + (size_t)a.x * DDIM + d);
  const float4 v0 = *(const float4*)(o0 + (size_t)a.y * DDIM + d);
  const float4 v1 = *(const float4*)(o1 + (size_t)a.y * DDIM + d);
  float4 r;
  r.x = p1 * (u0.x + u1.x) + p2 * (v0.x + v1.x);
  r.y = p1 * (u0.y + u1.y) + p2 * (v0.y + v1.y);
  r.z = p1 * (u0.z + u1.z) + p2 * (v0.z + v1.z);
  r.w = p1 * (u0.w + u1.w) + p2 * (v0.w + v1.w);
  *(float4*)(out + (size_t)n * DDIM + d) = r;
}

// ---------------- grouped GEMMs: 256x256, 8 waves, BK=32, 3-buffer pipeline -
// Per K-step per wave: vmcnt(4) -> s_barrier -> stage tile t+2 (4 loads) ->
// 12 ds_read_b128 (XOR-swizzled) -> 32 MFMA. Wave grid 2M x 4N (128x64 each).

// h[assign, :] = relu(x[btok[assign]] @ W1[e] + b1[e]);  N = HDIM, K = DDIM
__global__ void __launch_bounds__(512, 2) gemm1_kernel(
    const bf16_t* __restrict__ xb, const bf16_t* __restrict__ W1t,
    const float* __restrict__ b1, const int* __restrict__ btok,
    const int* __restrict__ offsets, const int* __restrict__ counts,
    const int* __restrict__ tmap, bf16_t* __restrict__ h) {
  const int job = xcd_swz((int)blockIdx.x, GRID1);
  const int tidx = job >> 4;   // 16 n-blocks per m-tile
  const int nblk = job & 15;
  if (tidx >= tmap[2 * MAX_MT]) return;
  const int e = tmap[tidx];
  const int m0 = tmap[MAX_MT + tidx];
  const int cnt = counts[e];
  const int aoff = offsets[e];
  const int n0 = nblk * 256;

  __shared__ __align__(16) bf16_t Al[3][256 * 32];  // 3 x 16 KB
  __shared__ __align__(16) bf16_t Bl[3][256 * 32];  // 3 x 16 KB

  const int tid = threadIdx.x;
  const int wave = tid >> 6;
  const int lane = tid & 63;

  // staging sources (pre-swizzled 16B slot), fixed over K
  const bf16_t* asrc[2];
  const bf16_t* bsrc[2];
#pragma unroll
  for (int j = 0; j < 2; ++j) {
    const int c = j * 512 + tid;           // 16B chunk id [0,1024)
    const int r = c >> 2;                  // tile row (4 slots per 64B row)
    const int slot = (c & 3) ^ ((r >> 1) & 3);
    int arow = m0 + r;
    if (arow > cnt - 1) arow = cnt - 1;    // clamp (stores masked later)
    asrc[j] = xb + (size_t)btok[aoff + arow] * DDIM + slot * 8;
    bsrc[j] = W1t + ((size_t)e * HDIM + n0 + r) * DDIM + slot * 8;
  }

  const int wr = (wave >> 2) * 128;  // wave M origin
  const int wc = (wave & 3) * 64;    // wave N origin
  const int lrow = lane & 15;
  const int lslot = lane >> 4;

  // per-lane swizzled read offsets (bytes within a buffer)
  int aoffb[8], boffb[4];
#pragma unroll
  for (int f = 0; f < 8; ++f) {
    const int Rr = wr + f * 16 + lrow;
    aoffb[f] = Rr * 64 + ((lslot ^ ((Rr >> 1) & 3)) << 4);
  }
#pragma unroll
  for (int f = 0; f < 4; ++f) {
    const int Cc = wc + f * 16 + lrow;
    boffb[f] = Cc * 64 + ((lslot ^ ((Cc >> 1) & 3)) << 4);
  }

  f32x4 acc[8][4];
#pragma unroll
  for (int mf = 0; mf < 8; ++mf)
#pragma unroll
    for (int nf = 0; nf < 4; ++nf) acc[mf][nf] = (f32x4){0.f, 0.f, 0.f, 0.f};

  auto stage = [&](int b, int t) {
    char* Ab = (char*)&Al[b][0] + wave * 1024;
    char* Bb = (char*)&Bl[b][0] + wave * 1024;
    const int ko = t * 32;
#pragma unroll
    for (int j = 0; j < 2; ++j) {
      GLOAD16(asrc[j] + ko, Ab + j * 8192);
      GLOAD16(bsrc[j] + ko, Bb + j * 8192);
    }
  };
  auto compute = [&](int b) {
    const char* Ab = (const char*)&Al[b][0];
    const char* Bb = (const char*)&Bl[b][0];
    bf16x8 af[8], bfr[4];
#pragma unroll
    for (int f = 0; f < 8; ++f) af[f] = *(const bf16x8*)(Ab + aoffb[f]);
#pragma unroll
    for (int f = 0; f < 4; ++f) bfr[f] = *(const bf16x8*)(Bb + boffb[f]);
    __builtin_amdgcn_s_setprio(1);
#pragma unroll
    for (int mf = 0; mf < 8; ++mf)
#pragma unroll
      for (int nf = 0; nf < 4; ++nf)
        acc[mf][nf] = __builtin_amdgcn_mfma_f32_16x16x32_bf16(
            af[mf], bfr[nf], acc[mf][nf], 0, 0, 0);
    __builtin_amdgcn_s_setprio(0);
  };

  // K pipeline: NT = 32 tiles of BK=32
  stage(0, 0);
  stage(1, 1);
  int cb = 0, pb = 2;
  for (int t = 0; t < 31; ++t) {
    VMCNT(4);
    __builtin_amdgcn_s_barrier();
    __builtin_amdgcn_sched_barrier(0x1);
    if (t + 2 < 32) stage(pb, t + 2);
    compute(cb);
    cb = (cb == 2) ? 0 : cb + 1;
    pb = (pb == 2) ? 0 : pb + 1;
  }
  VMCNT(0);
  __builtin_amdgcn_s_barrier();
  __builtin_amdgcn_sched_barrier(0x1);
  compute(cb);

  // epilogue: h = relu(acc + b1), bf16
  const int rbase = (lane >> 4) * 4;
  const float* b1e = b1 + (size_t)e * HDIM + n0;
#pragma unroll
  for (int nf = 0; nf < 4; ++nf) {
    const int cl = wc + nf * 16 + lrow;
    const float bb = b1e[cl];
#pragma unroll
    for (int mf = 0; mf < 8; ++mf) {
#pragma unroll
      for (int r = 0; r < 4; ++r) {
        const int grow = wr + mf * 16 + rbase + r;
        if (m0 + grow < cnt)
          h[(size_t)(aoff + m0 + grow) * HDIM + (n0 + cl)] =
              (bf16_t)fmaxf(acc[mf][nf][r] + bb, 0.f);
      }
    }
  }
}

// gemm2: per-assignment partials (no atomics) or atomic fallback.
// NT = K-steps per block; KSP = K-split factor; 4 n-blocks (DDIM/256).
template <int NT, int KSP, bool ATOMIC>
__global__ void __launch_bounds__(512, 2) gemm2_kernel(
    const bf16_t* __restrict__ h, const bf16_t* __restrict__ W2t,
    const float* __restrict__ b2, const int* __restrict__ btok,
    const float* __restrict__ bprob, const int* __restrict__ offsets,
    const int* __restrict__ counts, const int* __restrict__ tmap,
    float* __restrict__ o0, float* __restrict__ o1,
    float* __restrict__ out) {
  const int nwg = 4 * KSP * MAX_MT;
  const int job = xcd_swz((int)blockIdx.x, nwg);
  const int tidx = job / (4 * KSP);
  const int rem = job % (4 * KSP);
  const int nblk = rem & 3;
  const int kch = rem >> 2;
  if (tidx >= tmap[2 * MAX_MT]) return;
  const int e = tmap[tidx];
  const int m0 = tmap[MAX_MT + tidx];
  const int cnt = counts[e];
  const int aoff = offsets[e];
  const int n0 = nblk * 256;
  const int kbase = kch * (HDIM / KSP);

  __shared__ __align__(16) bf16_t Al[3][256 * 32];
  __shared__ __align__(16) bf16_t Bl[3][256 * 32];

  const int tid = threadIdx.x;
  const int wave = tid >> 6;
  const int lane = tid & 63;

  const bf16_t* asrc[2];
  const bf16_t* bsrc[2];
#pragma unroll
  for (int j = 0; j < 2; ++j) {
    const int c = j * 512 + tid;
    const int r = c >> 2;
    const int slot = (c & 3) ^ ((r >> 1) & 3);
    int arow = m0 + r;
    if (arow > cnt - 1) arow = cnt - 1;
    asrc[j] = h + (size_t)(aoff + arow) * HDIM + kbase + slot * 8;
    bsrc[j] = W2t + ((size_t)e * DDIM + n0 + r) * HDIM + kbase + slot * 8;
  }

  const int wr = (wave >> 2) * 128;
  const int wc = (wave & 3) * 64;
  const int lrow = lane & 15;
  const int lslot = lane >> 4;

  int aoffb[8], boffb[4];
#pragma unroll
  for (int f = 0; f < 8; ++f) {
    const int Rr = wr + f * 16 + lrow;
    aoffb[f] = Rr * 64 + ((lslot ^ ((Rr >> 1) & 3)) << 4);
  }
#pragma unroll
  for (int f = 0; f < 4; ++f) {
    const int Cc = wc + f * 16 + lrow;
    boffb[f] = Cc * 64 + ((lslot ^ ((Cc >> 1) & 3)) << 4);
  }

  f32x4 acc[8][4];
#pragma unroll
  for (int mf = 0; mf < 8; ++mf)
#pragma unroll
    for (int nf = 0; nf < 4; ++nf) acc[mf][nf] = (f32x4){0.f, 0.f, 0.f, 0.f};

  auto stage = [&](int b, int t) {
    char* Ab = (char*)&Al[b][0] + wave * 1024;
    char* Bb = (char*)&Bl[b][0] + wave * 1024;
    const int ko = t * 32;
#pragma unroll
    for (int j = 0; j < 2; ++j) {
      GLOAD16(asrc[j] + ko, Ab + j * 8192);
      GLOAD16(bsrc[j] + ko, Bb + j * 8192);
    }
  };
  auto compute = [&](int b) {
    const char* Ab = (const char*)&Al[b][0];
    const char* Bb = (const char*)&Bl[b][0];
    bf16x8 af[8], bfr[4];
#pragma unroll
    for (int f = 0; f < 8; ++f) af[f] = *(const bf16x8*)(Ab + aoffb[f]);
#pragma unroll
    for (int f = 0; f < 4; ++f) bfr[f] = *(const bf16x8*)(Bb + boffb[f]);
    __builtin_amdgcn_s_setprio(1);
#pragma unroll
    for (int mf = 0; mf < 8; ++mf)
#pragma unroll
      for (int nf = 0; nf < 4; ++nf)
        acc[mf][nf] = __builtin_amdgcn_mfma_f32_16x16x32_bf16(
            af[mf], bfr[nf], acc[mf][nf], 0, 0, 0);
    __builtin_amdgcn_s_setprio(0);
  };

  stage(0, 0);
  stage(1, 1);
  int cb = 0, pb = 2;
  for (int t = 0; t < NT - 1; ++t) {
    VMCNT(4);
    __builtin_amdgcn_s_barrier();
    __builtin_amdgcn_sched_barrier(0x1);
    if (t + 2 < NT) stage(pb, t + 2);
    compute(cb);
    cb = (cb == 2) ? 0 : cb + 1;
    pb = (pb == 2) ? 0 : pb + 1;
  }
  VMCNT(0);
  __builtin_amdgcn_s_barrier();
  __builtin_amdgcn_sched_barrier(0x1);
  compute(cb);

  const int rbase = (lane >> 4) * 4;
  const float* b2e = b2 + (size_t)e * DDIM + n0;
  float bb[4];
#pragma unroll
  for (int nf = 0; nf < 4; ++nf)
    bb[nf] = (kch == 0) ? b2e[wc + nf * 16 + lrow] : 0.f;

  if (ATOMIC) {
#pragma unroll
    for (int mf = 0; mf < 8; ++mf) {
#pragma unroll
      for (int r = 0; r < 4; ++r) {
        const int grow = wr + mf * 16 + rbase + r;
        if (m0 + grow < cnt) {
          const int assign = aoff + m0 + grow;
          const int tok = btok[assign];
          const float p = bprob[assign];
          float* orow = out + (size_t)tok * DDIM + n0;
#pragma unroll
          for (int nf = 0; nf < 4; ++nf) {
            const int cl = wc + nf * 16 + lrow;
            atomicAdd(&orow[cl], (acc[mf][nf][r] + bb[nf]) * p);
          }
        }
      }
    }
  } else {
    float* obase = (kch == 0) ? o0 : o1;
#pragma unroll
    for (int mf = 0; mf < 8; ++mf) {
#pragma unroll
      for (int r = 0; r < 4; ++r) {
        const int grow = wr + mf * 16 + rbase + r;
        if (m0 + grow < cnt) {
          const int assign = aoff + m0 + grow;
          float* orow = obase + (size_t)assign * DDIM + n0;
#pragma unroll
          for (int nf = 0; nf < 4; ++nf) {
            const int cl = wc + nf * 16 + lrow;
            orow[cl] = acc[mf][nf][r] + bb[nf];
          }
        }
      }
    }
  }
}

// ---------------- launch ----------------

extern "C" void kernel_launch(void* const* d_in, const int* in_sizes, int n_in,
                              void* d_out, int out_size, void* d_ws,
                              size_t ws_size, hipStream_t stream) {
  const float* x = (const float*)d_in[0];
  const float* Wr = (const float*)d_in[1];
  const float* br = (const float*)d_in[2];
  const float* W1 = (const float*)d_in[3];
  const float* b1 = (const float*)d_in[4];
  const float* W2 = (const float*)d_in[5];
  const float* b2 = (const float*)d_in[6];
  // d_in[7] = k (fixed 2, hardcoded)

  char* w = (char*)d_ws;
  auto alloc = [&](size_t bytes) -> char* {
    char* p = w;
    w += (bytes + 255) & ~(size_t)255;
    return p;
  };
  bf16_t* xb = (bf16_t*)alloc((size_t)NTOK * DDIM * 2);            // 16.8 MB
  bf16_t* W1t = (bf16_t*)alloc((size_t)NEXP * DDIM * HDIM * 2);    // 67.1 MB
  bf16_t* W2t = (bf16_t*)alloc((size_t)NEXP * DDIM * HDIM * 2);    // 67.1 MB
  bf16_t* hbuf = (bf16_t*)alloc((size_t)NASSIGN * HDIM * 2);       // 134 MB
  int* btok = (int*)alloc(NASSIGN * 4);
  float* bprob = (float*)alloc(NASSIGN * 4);
  int2* ids = (int2*)alloc(NTOK * 8);
  float2* prs = (float2*)alloc(NTOK * 8);
  int2* amap = (int2*)alloc(NTOK * 8);
  int* ctrl = (int*)alloc(64);     // counts[8] + cursor[8]
  int* offsets = (int*)alloc(64);  // 9 used
  int* tmap = (int*)alloc((2 * MAX_MT + 1) * 4);
  int* counts = ctrl;
  int* cursor = ctrl + 8;
  // o0: fresh region after everything; o1: overlays dead xb+W1t (67.1<83.9MB)
  const size_t osz = (size_t)NASSIGN * DDIM * 4;  // 67.1 MB
  float* o0 = (float*)alloc(osz);
  float* o1 = (float*)d_ws;  // valid only during/after gemm2 (xb,W1t dead)
  const size_t needed = (size_t)(w - (char*)d_ws);
  const bool pathA = ws_size >= needed;
  (void)in_sizes; (void)n_in;

  float* out = (float*)d_out;

  hipMemsetAsync(ctrl, 0, 64, stream);
  if (!pathA)
    hipMemsetAsync(d_out, 0, (size_t)out_size * 4, stream);  // atomics target

  transpose_cvt_kernel<<<dim3(HDIM / 32, DDIM / 64, NEXP), dim3(32, 8), 0,
                         stream>>>(W1, W1t, DDIM, HDIM);
  transpose_cvt_kernel<<<dim3(DDIM / 32, HDIM / 64, NEXP), dim3(32, 8), 0,
                         stream>>>(W2, W2t, HDIM, DDIM);
  router_kernel<<<NTOK, 256, 0, stream>>>(x, Wr, br, ids, prs, counts, xb);
  scan_aux_kernel<<<1, 256, 0, stream>>>(counts, offsets, tmap, ids, prs,
                                         out + (size_t)NTOK * DDIM);
  scatter_kernel<<<NTOK / 256, 256, 0, stream>>>(ids, prs, offsets, cursor,
                                                 btok, bprob, amap);
  gemm1_kernel<<<GRID1, 512, 0, stream>>>(xb, W1t, b1, btok, offsets, counts,
                                          tmap, hbuf);
  if (pathA) {
    gemm2_kernel<64, 2, false><<<GRID2A, 512, 0, stream>>>(
        hbuf, W2t, b2, btok, bprob, offsets, counts, tmap, o0, o1, out);
    combine_kernel<<<NTOK, 256, 0, stream>>>(o0, o1, amap, bprob, out);
  } else {
    gemm2_kernel<128, 1, true><<<GRID2B, 512, 0, stream>>>(
        hbuf, W2t, b2, btok, bprob, offsets, counts, tmap, o0, o1, out);
  }
}

// Round 8
// 824.764 us; speedup vs baseline: 1.1174x; 1.1174x over previous
//
#include <hip/hip_runtime.h>
#include <hip/hip_bf16.h>

// MoE: N=8192 tokens, D=1024, H=4096, E=8 experts, top-k=2.
// Grouped GEMMs: 256x256 tile, BK=64, 8 waves, 2 LDS buffers (128 KB),
// 4-phase-per-K-tile interleaved schedule (m201-style): per phase
// {ds_read quad, stage gloads, sched_barrier, s_barrier, setprio, 16 MFMA,
//  setprio, s_barrier}; one vmcnt(0) per K-tile at phase-3 exit.
// XOR-8 both-sides LDS swizzle. gemm2: atomic-free partials + combine.

#define NTOK 8192
#define DDIM 1024
#define HDIM 4096
#define NEXP 8
#define NASSIGN (NTOK * 2)
#define MAX_MT 72               // max ceil-sum of per-expert 256-row tiles (71)
#define GRID1 (16 * MAX_MT)     // 1152, divisible by 8
#define GRID2A (4 * 2 * MAX_MT) // 576  (K-split x2, no atomics)
#define GRID2B (4 * MAX_MT)     // 288  (atomic fallback)

typedef __bf16 bf16_t;
typedef __bf16 bf16x2 __attribute__((ext_vector_type(2)));
typedef __bf16 bf16x4 __attribute__((ext_vector_type(4)));
typedef __bf16 bf16x8 __attribute__((ext_vector_type(8)));
typedef float f32x4 __attribute__((ext_vector_type(4)));

#define GLOAD16(gptr, lptr)                                                    \
  __builtin_amdgcn_global_load_lds(                                            \
      (const __attribute__((address_space(1))) void*)(gptr),                   \
      (__attribute__((address_space(3))) void*)(lptr), 16, 0, 0)

#define VMCNT0 asm volatile("s_waitcnt vmcnt(0)" ::: "memory")

#define MFMA16(a, b, c) __builtin_amdgcn_mfma_f32_16x16x32_bf16(a, b, c, 0, 0, 0)

// bijective XCD swizzle: launched id -> logical job; nwg % 8 == 0
__device__ __forceinline__ int xcd_swz(int orig, int nwg) {
  const int cpx = nwg >> 3;
  return (orig & 7) * cpx + (orig >> 3);
}

// ---------------- weight transpose: [E][R][C] f32 -> [E][C][R] bf16 --------
__global__ void __launch_bounds__(256) transpose_cvt_kernel(
    const float* __restrict__ in, bf16_t* __restrict__ out, int R, int C) {
  __shared__ float tile[64][33];
  const size_t mat = (size_t)R * C;
  const float* ip = in + (size_t)blockIdx.z * mat;
  bf16_t* op = out + (size_t)blockIdx.z * mat;
  const int c0 = blockIdx.x * 32, r0 = blockIdx.y * 64;
  const int tx = threadIdx.x, ty = threadIdx.y;  // (32, 8)
#pragma unroll
  for (int i = 0; i < 8; ++i) {
    const int r = ty + 8 * i;
    tile[r][tx] = ip[(size_t)(r0 + r) * C + (c0 + tx)];
  }
  __syncthreads();
#pragma unroll
  for (int j = 0; j < 4; ++j) {
    const int c = ty + 8 * j;
    bf16x2 v;
    v[0] = (bf16_t)tile[2 * tx][c];
    v[1] = (bf16_t)tile[2 * tx + 1][c];
    *(bf16x2*)(op + (size_t)(c0 + c) * R + r0 + 2 * tx) = v;
  }
}

// ---------------- router (fused x -> bf16; wave-shuffle reduce) ------------
__global__ void __launch_bounds__(256) router_kernel(
    const float* __restrict__ x, const float* __restrict__ Wr,
    const float* __restrict__ br, int2* __restrict__ ids,
    float2* __restrict__ prs, int* __restrict__ counts,
    bf16_t* __restrict__ xb) {
  const int n = blockIdx.x;
  const int t = threadIdx.x;
  const int wave = t >> 6, lane = t & 63;
  const float4 xv = ((const float4*)(x + (size_t)n * DDIM))[t];
  bf16x4 o;
  o[0] = (bf16_t)xv.x; o[1] = (bf16_t)xv.y;
  o[2] = (bf16_t)xv.z; o[3] = (bf16_t)xv.w;
  ((bf16x4*)(xb + (size_t)n * DDIM))[t] = o;

  float acc[NEXP];
#pragma unroll
  for (int e = 0; e < NEXP; ++e) acc[e] = 0.f;
  const float xq[4] = {xv.x, xv.y, xv.z, xv.w};
#pragma unroll
  for (int q = 0; q < 4; ++q) {
    const float* w = Wr + (size_t)(4 * t + q) * NEXP;
#pragma unroll
    for (int e = 0; e < NEXP; ++e) acc[e] += xq[q] * w[e];
  }
#pragma unroll
  for (int off = 32; off >= 1; off >>= 1)
#pragma unroll
    for (int e = 0; e < NEXP; ++e) acc[e] += __shfl_down(acc[e], off);
  __shared__ float red[4][NEXP];
  if (lane == 0)
#pragma unroll
    for (int e = 0; e < NEXP; ++e) red[wave][e] = acc[e];
  __syncthreads();
  if (t == 0) {
    float l[NEXP];
#pragma unroll
    for (int e = 0; e < NEXP; ++e)
      l[e] = ((red[0][e] + red[1][e]) + (red[2][e] + red[3][e])) + br[e];
    int i1 = 0; float v1 = l[0];
    for (int e = 1; e < NEXP; ++e)
      if (l[e] > v1) { v1 = l[e]; i1 = e; }
    int i2 = (i1 == 0) ? 1 : 0; float v2 = l[i2];
    for (int e = 0; e < NEXP; ++e)
      if (e != i1 && l[e] > v2) { v2 = l[e]; i2 = e; }
    float denom = 0.f;
    for (int e = 0; e < NEXP; ++e) denom += expf(l[e] - v1);
    ids[n] = make_int2(i1, i2);
    prs[n] = make_float2(1.f / denom, expf(v2 - v1) / denom);
    atomicAdd(&counts[i1], 1);
    atomicAdd(&counts[i2], 1);
  }
}

// scan (thread 0, 256-row tiles) + aux loss
__global__ void __launch_bounds__(256) scan_aux_kernel(
    const int* __restrict__ counts, int* __restrict__ offsets,
    int* __restrict__ tmap, const int2* __restrict__ ids,
    const float2* __restrict__ prs, float* __restrict__ aux_out) {
  const int t = threadIdx.x;
  if (t == 0) {
    int off = 0, nt = 0;
    for (int e = 0; e < NEXP; ++e) {
      offsets[e] = off;
      const int c = counts[e];
      for (int m0 = 0; m0 < c; m0 += 256) {
        tmap[nt] = e;
        tmap[MAX_MT + nt] = m0;
        ++nt;
      }
      off += c;
    }
    offsets[NEXP] = off;
    tmap[2 * MAX_MT] = nt;
  }
  float imp[NEXP];
#pragma unroll
  for (int e = 0; e < NEXP; ++e) imp[e] = 0.f;
  for (int n = t; n < NTOK; n += 256) {
    const int2 id = ids[n];
    const float2 pr = prs[n];
#pragma unroll
    for (int e = 0; e < NEXP; ++e)
      imp[e] += (id.x == e ? pr.x : 0.f) + (id.y == e ? pr.y : 0.f);
  }
  __shared__ float red[256][NEXP];
#pragma unroll
  for (int e = 0; e < NEXP; ++e) red[t][e] = imp[e];
  __syncthreads();
  for (int s = 128; s >= 1; s >>= 1) {
    if (t < s) {
#pragma unroll
      for (int e = 0; e < NEXP; ++e) red[t][e] += red[t + s][e];
    }
    __syncthreads();
  }
  if (t == 0) {
    float m = 0.f;
    for (int e = 0; e < NEXP; ++e) m += red[0][e];
    m *= (1.f / NEXP);
    float v = 0.f;
    for (int e = 0; e < NEXP; ++e) {
      const float d = red[0][e] - m;
      v += d * d;
    }
    v *= (1.f / (NEXP - 1));  // ddof=1
    aux_out[0] = v / (m * m + 1e-9f);
  }
}

// scatter: bucket tokens; also record token -> (assign1, assign2)
__global__ void __launch_bounds__(256) scatter_kernel(
    const int2* __restrict__ ids, const float2* __restrict__ prs,
    const int* __restrict__ offsets, int* __restrict__ cursor,
    int* __restrict__ btok, float* __restrict__ bprob,
    int2* __restrict__ amap) {
  const int n = blockIdx.x * 256 + threadIdx.x;
  if (n >= NTOK) return;
  const int2 id = ids[n];
  const float2 pr = prs[n];
  int p = atomicAdd(&cursor[id.x], 1);
  const int a1 = offsets[id.x] + p;
  btok[a1] = n;
  bprob[a1] = pr.x;
  p = atomicAdd(&cursor[id.y], 1);
  const int a2 = offsets[id.y] + p;
  btok[a2] = n;
  bprob[a2] = pr.y;
  amap[n] = make_int2(a1, a2);
}

// combine: out[n] = p1*(o0+o1)[a1] + p2*(o0+o1)[a2]  (bias already in o0)
__global__ void __launch_bounds__(256) combine_kernel(
    const float* __restrict__ o0, const float* __restrict__ o1,
    const int2* __restrict__ amap, const float* __restrict__ bprob,
    float* __restrict__ out) {
  const int n = blockIdx.x;
  const int d = threadIdx.x * 4;
  const int2 a = amap[n];
  const float p1 = bprob[a.x], p2 = bprob[a.y];
  const float4 u0 = *(const float4*)(o0 + (size_t)a.x * DDIM + d);
  const float4 u1 = *(const float4*)(o1 + (size_t)a.x * DDIM + d);
  const float4 v0 = *(const float4*)(o0 + (size_t)a.y * DDIM + d);
  const float4 v1 = *(const float4*)(o1 + (size_t)a.y * DDIM + d);
  float4 r;
  r.x = p1 * (u0.x + u1.x) + p2 * (v0.x + v1.x);
  r.y = p1 * (u0.y + u1.y) + p2 * (v0.y + v1.y);
  r.z = p1 * (u0.z + u1.z) + p2 * (v0.z + v1.z);
  r.w = p1 * (u0.w + u1.w) + p2 * (v0.w + v1.w);
  *(float4*)(out + (size_t)n * DDIM + d) = r;
}

// ---------------- shared K-loop machinery (macros) --------------------------
// LDS: Al[2][256*64], Bl[2][256*64] bf16 (2 x 32KB each side, 128KB total).
// Stage: sweep s deposits chunks c=s*512+tid at byte c*16; row=c>>3, phys
// slot p=c&7 carries logical slot l=p^(row&7) (source k-offset l*8 elems).
// Read: byte = row*128 + ((ks*4+lslot)^(row&7))*16; ks toggle = XOR 64.

#define STAGE_A(BUF, KO)                                                       \
  GLOAD16(asrc0 + (KO), (char*)Al + (BUF)*32768 + 0*8192 + wave*1024);         \
  GLOAD16(asrc1 + (KO), (char*)Al + (BUF)*32768 + 1*8192 + wave*1024);         \
  GLOAD16(asrc2 + (KO), (char*)Al + (BUF)*32768 + 2*8192 + wave*1024);         \
  GLOAD16(asrc3 + (KO), (char*)Al + (BUF)*32768 + 3*8192 + wave*1024);

#define STAGE_B(BUF, KO)                                                       \
  GLOAD16(bsrc0 + (KO), (char*)Bl + (BUF)*32768 + 0*8192 + wave*1024);         \
  GLOAD16(bsrc1 + (KO), (char*)Bl + (BUF)*32768 + 1*8192 + wave*1024);         \
  GLOAD16(bsrc2 + (KO), (char*)Bl + (BUF)*32768 + 2*8192 + wave*1024);         \
  GLOAD16(bsrc3 + (KO), (char*)Bl + (BUF)*32768 + 3*8192 + wave*1024);

#define LOAD_AF(O0, O1, O2, O3, KX)                                            \
  af0 = *(const bf16x8*)(Ac + ((O0) ^ (KX)));                                  \
  af1 = *(const bf16x8*)(Ac + ((O1) ^ (KX)));                                  \
  af2 = *(const bf16x8*)(Ac + ((O2) ^ (KX)));                                  \
  af3 = *(const bf16x8*)(Ac + ((O3) ^ (KX)));

#define LOAD_BF(KX)                                                            \
  bf0 = *(const bf16x8*)(Bc + (boffb0 ^ (KX)));                                \
  bf1 = *(const bf16x8*)(Bc + (boffb1 ^ (KX)));                                \
  bf2 = *(const bf16x8*)(Bc + (boffb2 ^ (KX)));                                \
  bf3 = *(const bf16x8*)(Bc + (boffb3 ^ (KX)));

#define MROW(M, A)                                                             \
  acc[M][0] = MFMA16(A, bf0, acc[M][0]);                                       \
  acc[M][1] = MFMA16(A, bf1, acc[M][1]);                                       \
  acc[M][2] = MFMA16(A, bf2, acc[M][2]);                                       \
  acc[M][3] = MFMA16(A, bf3, acc[M][3]);

#define PH_MFMA(MB)                                                            \
  __builtin_amdgcn_s_setprio(1);                                               \
  MROW(MB + 0, af0) MROW(MB + 1, af1) MROW(MB + 2, af2) MROW(MB + 3, af3)      \
  __builtin_amdgcn_s_setprio(0);

#define PH_ENTER                                                               \
  __builtin_amdgcn_sched_barrier(0x1);                                         \
  __builtin_amdgcn_s_barrier();

#define PH_EXIT __builtin_amdgcn_s_barrier();

// 4-phase K-tile loop; buffers alternate; one vmcnt(0) per tile at ph3 exit.
#define KLOOP(NT)                                                              \
  STAGE_A(0, 0)                                                                \
  STAGE_B(0, 0)                                                                \
  VMCNT0;                                                                      \
  __builtin_amdgcn_s_barrier();                                                \
  __builtin_amdgcn_sched_barrier(0);                                           \
  _Pragma("unroll 2") for (int t = 0; t < (NT); ++t) {                         \
    const int cb = t & 1, nc = cb ^ 1;                                         \
    const int ko = (t + 1) * 64;                                               \
    const char* Ac = (const char*)Al + cb * 32768;                             \
    const char* Bc = (const char*)Bl + cb * 32768;                             \
    const bool pf = (t + 1 < (NT));                                            \
    bf16x8 af0, af1, af2, af3, bf0, bf1, bf2, bf3;                             \
    /* phase 0: A[mh0,ks0] + B[ks0]; stage A(t+1) */                           \
    LOAD_AF(aoffb0, aoffb1, aoffb2, aoffb3, 0)                                 \
    LOAD_BF(0)                                                                 \
    if (pf) { STAGE_A(nc, ko) }                                                \
    PH_ENTER                                                                   \
    PH_MFMA(0)                                                                 \
    PH_EXIT                                                                    \
    /* phase 1: A[mh1,ks0]; stage B(t+1) */                                    \
    LOAD_AF(aoffb4, aoffb5, aoffb6, aoffb7, 0)                                 \
    if (pf) { STAGE_B(nc, ko) }                                                \
    PH_ENTER                                                                   \
    PH_MFMA(4)                                                                 \
    PH_EXIT                                                                    \
    /* phase 2: A[mh0,ks1] + B[ks1] */                                         \
    LOAD_AF(aoffb0, aoffb1, aoffb2, aoffb3, 64)                                \
    LOAD_BF(64)                                                                \
    PH_ENTER                                                                   \
    PH_MFMA(0)                                                                 \
    PH_EXIT                                                                    \
    /* phase 3: A[mh1,ks1]; tile-boundary drain */                             \
    LOAD_AF(aoffb4, aoffb5, aoffb6, aoffb7, 64)                                \
    PH_ENTER                                                                   \
    PH_MFMA(4)                                                                 \
    VMCNT0;                                                                    \
    __builtin_amdgcn_s_barrier();                                              \
    __builtin_amdgcn_sched_barrier(0);                                         \
  }

// common per-thread geometry setup (names used by KLOOP)
#define GEOM_SETUP                                                             \
  const int tid = threadIdx.x;                                                 \
  const int wave = tid >> 6;                                                   \
  const int lane = tid & 63;                                                   \
  const int wr = (wave >> 2) * 128;                                            \
  const int wc = (wave & 3) * 64;                                              \
  const int lrow = lane & 15;                                                  \
  const int lslot = lane >> 4;                                                 \
  const int sxor = ((lslot ^ (lrow & 7)) << 4);                                \
  const int aoffb0 = (wr + 0 * 16 + lrow) * 128 + sxor;                        \
  const int aoffb1 = (wr + 1 * 16 + lrow) * 128 + sxor;                        \
  const int aoffb2 = (wr + 2 * 16 + lrow) * 128 + sxor;                        \
  const int aoffb3 = (wr + 3 * 16 + lrow) * 128 + sxor;                        \
  const int aoffb4 = (wr + 4 * 16 + lrow) * 128 + sxor;                        \
  const int aoffb5 = (wr + 5 * 16 + lrow) * 128 + sxor;                        \
  const int aoffb6 = (wr + 6 * 16 + lrow) * 128 + sxor;                        \
  const int aoffb7 = (wr + 7 * 16 + lrow) * 128 + sxor;                        \
  const int boffb0 = (wc + 0 * 16 + lrow) * 128 + sxor;                        \
  const int boffb1 = (wc + 1 * 16 + lrow) * 128 + sxor;                        \
  const int boffb2 = (wc + 2 * 16 + lrow) * 128 + sxor;                        \
  const int boffb3 = (wc + 3 * 16 + lrow) * 128 + sxor;

// per-sweep stage source row/slot (s = sweep 0..3)
#define SRC_ROW(S) ((S)*64 + (tid >> 3))
#define SRC_SLOT ((tid & 7))

// h[assign, :] = relu(x[btok[assign]] @ W1[e] + b1[e]);  N = HDIM, K = DDIM
__global__ void __launch_bounds__(512, 2) gemm1_kernel(
    const bf16_t* __restrict__ xb, const bf16_t* __restrict__ W1t,
    const float* __restrict__ b1, const int* __restrict__ btok,
    const int* __restrict__ offsets, const int* __restrict__ counts,
    const int* __restrict__ tmap, bf16_t* __restrict__ h) {
  const int job = xcd_swz((int)blockIdx.x, GRID1);
  const int tidx = job >> 4;   // 16 n-blocks per m-tile
  const int nblk = job & 15;
  if (tidx >= tmap[2 * MAX_MT]) return;
  const int e = tmap[tidx];
  const int m0 = tmap[MAX_MT + tidx];
  const int cnt = counts[e];
  const int aoff = offsets[e];
  const int n0 = nblk * 256;

  __shared__ __align__(16) bf16_t Al[2][256 * 64];  // 64 KB
  __shared__ __align__(16) bf16_t Bl[2][256 * 64];  // 64 KB

  GEOM_SETUP

  // stage sources (pre-swizzled): logical slot l = phys ^ (row&7)
  const bf16_t *asrc0, *asrc1, *asrc2, *asrc3;
  const bf16_t *bsrc0, *bsrc1, *bsrc2, *bsrc3;
  {
    const int p = SRC_SLOT;
#pragma unroll
    for (int s = 0; s < 4; ++s) {
      const int row = SRC_ROW(s);
      const int l = p ^ (row & 7);
      int arow = m0 + row;
      if (arow > cnt - 1) arow = cnt - 1;  // clamp (stores masked later)
      const bf16_t* ap = xb + (size_t)btok[aoff + arow] * DDIM + l * 8;
      const bf16_t* bp = W1t + ((size_t)e * HDIM + n0 + row) * DDIM + l * 8;
      if (s == 0) { asrc0 = ap; bsrc0 = bp; }
      else if (s == 1) { asrc1 = ap; bsrc1 = bp; }
      else if (s == 2) { asrc2 = ap; bsrc2 = bp; }
      else { asrc3 = ap; bsrc3 = bp; }
    }
  }

  f32x4 acc[8][4];
#pragma unroll
  for (int mf = 0; mf < 8; ++mf)
#pragma unroll
    for (int nf = 0; nf < 4; ++nf) acc[mf][nf] = (f32x4){0.f, 0.f, 0.f, 0.f};

  KLOOP(16)  // K = 1024 = 16 x 64

  // epilogue: h = relu(acc + b1), bf16  (r7-validated)
  const int rbase = (lane >> 4) * 4;
  const float* b1e = b1 + (size_t)e * HDIM + n0;
#pragma unroll
  for (int nf = 0; nf < 4; ++nf) {
    const int cl = wc + nf * 16 + lrow;
    const float bb = b1e[cl];
#pragma unroll
    for (int mf = 0; mf < 8; ++mf) {
#pragma unroll
      for (int r = 0; r < 4; ++r) {
        const int grow = wr + mf * 16 + rbase + r;
        if (m0 + grow < cnt)
          h[(size_t)(aoff + m0 + grow) * HDIM + (n0 + cl)] =
              (bf16_t)fmaxf(acc[mf][nf][r] + bb, 0.f);
      }
    }
  }
}

// gemm2: per-assignment partials (no atomics) or atomic fallback.
template <int NT, int KSP, bool ATOMIC>
__global__ void __launch_bounds__(512, 2) gemm2_kernel(
    const bf16_t* __restrict__ h, const bf16_t* __restrict__ W2t,
    const float* __restrict__ b2, const int* __restrict__ btok,
    const float* __restrict__ bprob, const int* __restrict__ offsets,
    const int* __restrict__ counts, const int* __restrict__ tmap,
    float* __restrict__ o0, float* __restrict__ o1,
    float* __restrict__ out) {
  const int nwg = 4 * KSP * MAX_MT;
  const int job = xcd_swz((int)blockIdx.x, nwg);
  const int tidx = job / (4 * KSP);
  const int rem = job % (4 * KSP);
  const int nblk = rem & 3;
  const int kch = rem >> 2;
  if (tidx >= tmap[2 * MAX_MT]) return;
  const int e = tmap[tidx];
  const int m0 = tmap[MAX_MT + tidx];
  const int cnt = counts[e];
  const int aoff = offsets[e];
  const int n0 = nblk * 256;
  const int kbase = kch * (HDIM / KSP);

  __shared__ __align__(16) bf16_t Al[2][256 * 64];
  __shared__ __align__(16) bf16_t Bl[2][256 * 64];

  GEOM_SETUP

  const bf16_t *asrc0, *asrc1, *asrc2, *asrc3;
  const bf16_t *bsrc0, *bsrc1, *bsrc2, *bsrc3;
  {
    const int p = SRC_SLOT;
#pragma unroll
    for (int s = 0; s < 4; ++s) {
      const int row = SRC_ROW(s);
      const int l = p ^ (row & 7);
      int arow = m0 + row;
      if (arow > cnt - 1) arow = cnt - 1;
      const bf16_t* ap = h + (size_t)(aoff + arow) * HDIM + kbase + l * 8;
      const bf16_t* bp =
          W2t + ((size_t)e * DDIM + n0 + row) * HDIM + kbase + l * 8;
      if (s == 0) { asrc0 = ap; bsrc0 = bp; }
      else if (s == 1) { asrc1 = ap; bsrc1 = bp; }
      else if (s == 2) { asrc2 = ap; bsrc2 = bp; }
      else { asrc3 = ap; bsrc3 = bp; }
    }
  }

  f32x4 acc[8][4];
#pragma unroll
  for (int mf = 0; mf < 8; ++mf)
#pragma unroll
    for (int nf = 0; nf < 4; ++nf) acc[mf][nf] = (f32x4){0.f, 0.f, 0.f, 0.f};

  KLOOP(NT)

  // epilogue (r6/r7-validated)
  const int rbase = (lane >> 4) * 4;
  const float* b2e = b2 + (size_t)e * DDIM + n0;
  float bb[4];
#pragma unroll
  for (int nf = 0; nf < 4; ++nf)
    bb[nf] = (kch == 0) ? b2e[wc + nf * 16 + lrow] : 0.f;

  if (ATOMIC) {
#pragma unroll
    for (int mf = 0; mf < 8; ++mf) {
#pragma unroll
      for (int r = 0; r < 4; ++r) {
        const int grow = wr + mf * 16 + rbase + r;
        if (m0 + grow < cnt) {
          const int assign = aoff + m0 + grow;
          const int tok = btok[assign];
          const float p = bprob[assign];
          float* orow = out + (size_t)tok * DDIM + n0;
#pragma unroll
          for (int nf = 0; nf < 4; ++nf) {
            const int cl = wc + nf * 16 + lrow;
            atomicAdd(&orow[cl], (acc[mf][nf][r] + bb[nf]) * p);
          }
        }
      }
    }
  } else {
    float* obase = (kch == 0) ? o0 : o1;
#pragma unroll
    for (int mf = 0; mf < 8; ++mf) {
#pragma unroll
      for (int r = 0; r < 4; ++r) {
        const int grow = wr + mf * 16 + rbase + r;
        if (m0 + grow < cnt) {
          const int assign = aoff + m0 + grow;
          float* orow = obase + (size_t)assign * DDIM + n0;
#pragma unroll
          for (int nf = 0; nf < 4; ++nf) {
            const int cl = wc + nf * 16 + lrow;
            orow[cl] = acc[mf][nf][r] + bb[nf];
          }
        }
      }
    }
  }
}

// ---------------- launch ----------------

extern "C" void kernel_launch(void* const* d_in, const int* in_sizes, int n_in,
                              void* d_out, int out_size, void* d_ws,
                              size_t ws_size, hipStream_t stream) {
  const float* x = (const float*)d_in[0];
  const float* Wr = (const float*)d_in[1];
  const float* br = (const float*)d_in[2];
  const float* W1 = (const float*)d_in[3];
  const float* b1 = (const float*)d_in[4];
  const float* W2 = (const float*)d_in[5];
  const float* b2 = (const float*)d_in[6];
  // d_in[7] = k (fixed 2, hardcoded)

  char* w = (char*)d_ws;
  auto alloc = [&](size_t bytes) -> char* {
    char* p = w;
    w += (bytes + 255) & ~(size_t)255;
    return p;
  };
  bf16_t* xb = (bf16_t*)alloc((size_t)NTOK * DDIM * 2);            // 16.8 MB
  bf16_t* W1t = (bf16_t*)alloc((size_t)NEXP * DDIM * HDIM * 2);    // 67.1 MB
  bf16_t* W2t = (bf16_t*)alloc((size_t)NEXP * DDIM * HDIM * 2);    // 67.1 MB
  bf16_t* hbuf = (bf16_t*)alloc((size_t)NASSIGN * HDIM * 2);       // 134 MB
  int* btok = (int*)alloc(NASSIGN * 4);
  float* bprob = (float*)alloc(NASSIGN * 4);
  int2* ids = (int2*)alloc(NTOK * 8);
  float2* prs = (float2*)alloc(NTOK * 8);
  int2* amap = (int2*)alloc(NTOK * 8);
  int* ctrl = (int*)alloc(64);     // counts[8] + cursor[8]
  int* offsets = (int*)alloc(64);  // 9 used
  int* tmap = (int*)alloc((2 * MAX_MT + 1) * 4);
  int* counts = ctrl;
  int* cursor = ctrl + 8;
  // o0: fresh region after everything; o1: overlays dead xb+W1t (67.1<83.9MB)
  const size_t osz = (size_t)NASSIGN * DDIM * 4;  // 67.1 MB
  float* o0 = (float*)alloc(osz);
  float* o1 = (float*)d_ws;  // valid only during/after gemm2 (xb,W1t dead)
  const size_t needed = (size_t)(w - (char*)d_ws);
  const bool pathA = ws_size >= needed;
  (void)in_sizes; (void)n_in;

  float* out = (float*)d_out;

  hipMemsetAsync(ctrl, 0, 64, stream);
  if (!pathA)
    hipMemsetAsync(d_out, 0, (size_t)out_size * 4, stream);  // atomics target

  transpose_cvt_kernel<<<dim3(HDIM / 32, DDIM / 64, NEXP), dim3(32, 8), 0,
                         stream>>>(W1, W1t, DDIM, HDIM);
  transpose_cvt_kernel<<<dim3(DDIM / 32, HDIM / 64, NEXP), dim3(32, 8), 0,
                         stream>>>(W2, W2t, HDIM, DDIM);
  router_kernel<<<NTOK, 256, 0, stream>>>(x, Wr, br, ids, prs, counts, xb);
  scan_aux_kernel<<<1, 256, 0, stream>>>(counts, offsets, tmap, ids, prs,
                                         out + (size_t)NTOK * DDIM);
  scatter_kernel<<<NTOK / 256, 256, 0, stream>>>(ids, prs, offsets, cursor,
                                                 btok, bprob, amap);
  gemm1_kernel<<<GRID1, 512, 0, stream>>>(xb, W1t, b1, btok, offsets, counts,
                                          tmap, hbuf);
  if (pathA) {
    gemm2_kernel<32, 2, false><<<GRID2A, 512, 0, stream>>>(
        hbuf, W2t, b2, btok, bprob, offsets, counts, tmap, o0, o1, out);
    combine_kernel<<<NTOK, 256, 0, stream>>>(o0, o1, amap, bprob, out);
  } else {
    gemm2_kernel<64, 1, true><<<GRID2B, 512, 0, stream>>>(
        hbuf, W2t, b2, btok, bprob, offsets, counts, tmap, o0, o1, out);
  }
}